// Round 2
// baseline (7208.166 us; speedup 1.0000x reference)
//
#include <hip/hip_runtime.h>

typedef __attribute__((ext_vector_type(8))) short bf8_t;
typedef __attribute__((ext_vector_type(4))) float f32x4;
typedef __attribute__((ext_vector_type(4))) unsigned short us4;

#define S_LEN 2048
#define NCHUNK 16
#define CHUNK_TARGET 384u
#define GI_BYTES (65536ULL * 1536ULL * 2ULL)

static __device__ __forceinline__ unsigned short f2bf(float f) {
  union { float f; unsigned u; } v; v.f = f;
  unsigned r = v.u + 0x7FFFu + ((v.u >> 16) & 1u);
  return (unsigned short)(r >> 16);
}
static __device__ __forceinline__ float bf2f(unsigned short u) {
  union { unsigned u; float f; } v; v.u = ((unsigned)u) << 16;
  return v.f;
}
static __device__ __forceinline__ float sigm(float x) {
  x = fminf(fmaxf(x, -20.f), 20.f);
  return __builtin_amdgcn_rcpf(1.f + __expf(-x));
}
static __device__ __forceinline__ float tanh_(float x) {
  x = fminf(fmaxf(x, -20.f), 20.f);
  float e = __expf(2.f * x);
  return 1.f - 2.f * __builtin_amdgcn_rcpf(e + 1.f);
}
static __device__ __forceinline__ f32x4 MFMA(bf8_t a, bf8_t b, f32x4 c) {
  return __builtin_amdgcn_mfma_f32_16x16x32_bf16(a, b, c, 0, 0, 0);
}

__global__ void zero_flags_k(unsigned int* f) {
  if (threadIdx.x < NCHUNK) f[threadIdx.x] = 0u;
}

// ---------------------------------------------------------------------------
// Fused kernel. Blocks 0-3: GRU recurrence, block = (dir, 16-batch group).
// Blocks 4..6147: gi GEMM (128x128 tiles), chunk-ordered 0,15,1,14,... with
// per-chunk release counters; rec blocks acquire-poll before each 128-t chunk.
// ---------------------------------------------------------------------------
__global__ __launch_bounds__(512, 2) void fused_k(
    const float* __restrict__ v_in,
    const float* __restrict__ Wif, const float* __restrict__ Whf,
    const float* __restrict__ bif, const float* __restrict__ bhf,
    const float* __restrict__ Wib, const float* __restrict__ Whb,
    const float* __restrict__ bib, const float* __restrict__ bhb,
    const int* __restrict__ clp,
    unsigned short* __restrict__ gi,
    unsigned int* flags,
    float* __restrict__ out)
{
  const int bid = blockIdx.x;
  const int tid = threadIdx.x;
  const int lane = tid & 63, wave = tid >> 6;
  const int l15 = lane & 15, l4 = lane >> 4;

  __shared__ __align__(16) unsigned short As[128][40];
  __shared__ __align__(16) unsigned short Bs[128][40];
  __shared__ __align__(16) unsigned short hlds[16][264];

  if (bid >= 4) {
    // ---------------- GEMM: gi = [X@Wf^T + bias_f | X@Wb^T + bias_b] --------
    const int gidb = bid - 4;
    const int cr = gidb / 384, sub = gidb % 384;
    const int bb = sub / 12, nb = sub % 12;
    const int c = (cr & 1) ? (15 - (cr >> 1)) : (cr >> 1);  // chunk emission order
    const int m0 = bb * 2048 + c * 128;
    const int n0 = nb * 128;
    const int wm = wave >> 2, wn = wave & 3;   // 2 x 4 wave grid, 64x32 per wave

    f32x4 acc[4][2];
#pragma unroll
    for (int a = 0; a < 4; ++a)
#pragma unroll
      for (int b = 0; b < 2; ++b) acc[a][b] = f32x4{0.f, 0.f, 0.f, 0.f};

    for (int k0 = 0; k0 < 256; k0 += 32) {
#pragma unroll
      for (int i = 0; i < 2; ++i) {
        int u = tid + 512 * i;          // 1024 units: 128 rows x 8 quads
        int r = u >> 3, q = u & 7;
        float4 va = *(const float4*)(v_in + (size_t)(m0 + r) * 256 + k0 + q * 4);
        unsigned long long pka =
            (unsigned long long)((unsigned)f2bf(va.x) | ((unsigned)f2bf(va.y) << 16)) |
            ((unsigned long long)((unsigned)f2bf(va.z) | ((unsigned)f2bf(va.w) << 16)) << 32);
        *(unsigned long long*)&As[r][q * 4] = pka;
        int cg = n0 + r;
        const float* pb = (cg < 768) ? (Wif + (size_t)cg * 256)
                                     : (Wib + (size_t)(cg - 768) * 256);
        float4 vbv = *(const float4*)(pb + k0 + q * 4);
        unsigned long long pkb =
            (unsigned long long)((unsigned)f2bf(vbv.x) | ((unsigned)f2bf(vbv.y) << 16)) |
            ((unsigned long long)((unsigned)f2bf(vbv.z) | ((unsigned)f2bf(vbv.w) << 16)) << 32);
        *(unsigned long long*)&Bs[r][q * 4] = pkb;
      }
      __syncthreads();
      bf8_t af[4], bv2[2];
#pragma unroll
      for (int mt = 0; mt < 4; ++mt)
        af[mt] = *(const bf8_t*)&As[wm * 64 + mt * 16 + l15][l4 * 8];
#pragma unroll
      for (int nt = 0; nt < 2; ++nt)
        bv2[nt] = *(const bf8_t*)&Bs[wn * 32 + nt * 16 + l15][l4 * 8];
#pragma unroll
      for (int mt = 0; mt < 4; ++mt)
#pragma unroll
        for (int nt = 0; nt < 2; ++nt)
          acc[mt][nt] = MFMA(af[mt], bv2[nt], acc[mt][nt]);
      __syncthreads();
    }
#pragma unroll
    for (int nt = 0; nt < 2; ++nt) {
      int col = n0 + wn * 32 + nt * 16 + l15;
      int col3 = (col < 768) ? col : col - 768;
      int gate = col3 >> 8;
      // fold b_ih (all gates) + b_hh (r,z only; n's b_hh is inside r*(...))
      float bias = ((col < 768) ? bif[col3] : bib[col3]) +
                   ((gate < 2) ? ((col < 768) ? bhf[col3] : bhb[col3]) : 0.f);
#pragma unroll
      for (int mt = 0; mt < 4; ++mt) {
        int row = m0 + wm * 64 + mt * 16 + l4 * 4;
#pragma unroll
        for (int q = 0; q < 4; ++q)
          gi[(size_t)(row + q) * 1536 + col] = f2bf(acc[mt][nt][q] + bias);
      }
    }
    __syncthreads();  // drains vmcnt: all stores of this block complete
    if (tid == 0)
      __hip_atomic_fetch_add(&flags[c], 1u, __ATOMIC_RELEASE, __HIP_MEMORY_SCOPE_AGENT);
    return;
  }

  // ---------------- Recurrence: block = (dir, group of 16 batches) ----------
  const int dir = bid & 1;
  const int batch = (bid >> 1) * 16 + l15;
  const int cl = clp[0];
  const int rows = S_LEN - 2 * cl;
  const float* Wh = dir ? Whb : Whf;
  const float* bh = dir ? bhb : bhf;
  const int h00 = wave * 16 + l4 * 4;   // hidden base, hg=0
  const int h01 = h00 + 128;            // hg=1

  // persistent W_hh fragments: A[c][gate*2+hg], 192 VGPRs/thread
  bf8_t A[8][6];
#pragma unroll
  for (int gg = 0; gg < 6; ++gg) {
    const int g = gg >> 1, hg = gg & 1;
    const int row = g * 256 + (wave + 8 * hg) * 16 + l15;
    const float* wr = Wh + (size_t)row * 256 + l4 * 8;
#pragma unroll
    for (int c = 0; c < 8; ++c) {
      float4 w0 = *(const float4*)(wr + c * 32);
      float4 w1 = *(const float4*)(wr + c * 32 + 4);
      bf8_t f;
      f[0] = (short)f2bf(w0.x); f[1] = (short)f2bf(w0.y);
      f[2] = (short)f2bf(w0.z); f[3] = (short)f2bf(w0.w);
      f[4] = (short)f2bf(w1.x); f[5] = (short)f2bf(w1.y);
      f[6] = (short)f2bf(w1.z); f[7] = (short)f2bf(w1.w);
      A[c][gg] = f;
    }
  }
  const f32x4 bhn0 = *(const f32x4*)(bh + 512 + h00);
  const f32x4 bhn1 = *(const f32x4*)(bh + 512 + h01);

  for (int i = tid; i < 16 * 264; i += 512) ((unsigned short*)hlds)[i] = 0;
  __syncthreads();

  const unsigned short* gib = gi + (size_t)batch * S_LEN * 1536 + dir * 768;
  const float* vb = v_in + (size_t)batch * S_LEN * 256;
  float* ob = out + (size_t)batch * rows * 512 + dir * 256;

#pragma unroll 1
  for (int s = 0; s < S_LEN; ++s) {
    const int t = dir ? (S_LEN - 1 - s) : s;
    if ((t & 127) == (dir ? 127 : 0)) {     // entering a new 128-t chunk
      if (tid == 0) {
        unsigned int* fp = &flags[t >> 7];
        while (__hip_atomic_load(fp, __ATOMIC_RELAXED, __HIP_MEMORY_SCOPE_AGENT) < CHUNK_TARGET)
          __builtin_amdgcn_s_sleep(16);
        (void)__hip_atomic_load(fp, __ATOMIC_ACQUIRE, __HIP_MEMORY_SCOPE_AGENT);
      }
      __syncthreads();
    }
    // issue this step's global loads early; consumed after the MFMA phase
    const unsigned short* gt = gib + (size_t)t * 1536;
    const us4 LR0 = *(const us4*)(gt + h00);
    const us4 LZ0 = *(const us4*)(gt + 256 + h00);
    const us4 LN0 = *(const us4*)(gt + 512 + h00);
    const us4 LR1 = *(const us4*)(gt + h01);
    const us4 LZ1 = *(const us4*)(gt + 256 + h01);
    const us4 LN1 = *(const us4*)(gt + 512 + h01);
    const float* vt = vb + (size_t)t * 256;
    const float4 V0 = *(const float4*)(vt + h00);
    const float4 V1 = *(const float4*)(vt + h01);
    const us4 HO0 = *(const us4*)&hlds[l15][h00];   // own slot: no race
    const us4 HO1 = *(const us4*)&hlds[l15][h01];

    f32x4 aR0 = {0.f,0.f,0.f,0.f}, aZ0 = aR0, aN0 = aR0;
    f32x4 aR1 = aR0, aZ1 = aR0, aN1 = aR0;
#pragma unroll
    for (int c = 0; c < 8; ++c) {
      const bf8_t bv = *(const bf8_t*)&hlds[l15][c * 32 + l4 * 8];
      aR0 = MFMA(A[c][0], bv, aR0);
      aR1 = MFMA(A[c][1], bv, aR1);
      aZ0 = MFMA(A[c][2], bv, aZ0);
      aZ1 = MFMA(A[c][3], bv, aZ1);
      aN0 = MFMA(A[c][4], bv, aN0);
      aN1 = MFMA(A[c][5], bv, aN1);
    }
    __syncthreads();   // A: all hlds reads complete before any h2 write

    float h20[4], h21[4];
#pragma unroll
    for (int q = 0; q < 4; ++q) {
      const float r = sigm(aR0[q] + bf2f(LR0[q]));
      const float z = sigm(aZ0[q] + bf2f(LZ0[q]));
      const float n = tanh_(bf2f(LN0[q]) + r * (aN0[q] + bhn0[q]));
      const float ho = bf2f(HO0[q]);
      h20[q] = n + z * (ho - n);
    }
#pragma unroll
    for (int q = 0; q < 4; ++q) {
      const float r = sigm(aR1[q] + bf2f(LR1[q]));
      const float z = sigm(aZ1[q] + bf2f(LZ1[q]));
      const float n = tanh_(bf2f(LN1[q]) + r * (aN1[q] + bhn1[q]));
      const float ho = bf2f(HO1[q]);
      h21[q] = n + z * (ho - n);
    }
    us4 w0, w1;
    w0[0] = f2bf(h20[0]); w0[1] = f2bf(h20[1]); w0[2] = f2bf(h20[2]); w0[3] = f2bf(h20[3]);
    w1[0] = f2bf(h21[0]); w1[1] = f2bf(h21[1]); w1[2] = f2bf(h21[2]); w1[3] = f2bf(h21[3]);
    *(us4*)&hlds[l15][h00] = w0;
    *(us4*)&hlds[l15][h01] = w1;

    if (s >= cl && s < S_LEN - cl) {
      const float4 o0 = {h20[0] + V0.x, h20[1] + V0.y, h20[2] + V0.z, h20[3] + V0.w};
      const float4 o1 = {h21[0] + V1.x, h21[1] + V1.y, h21[2] + V1.z, h21[3] + V1.w};
      *(float4*)(ob + (size_t)(s - cl) * 512 + h00) = o0;
      *(float4*)(ob + (size_t)(s - cl) * 512 + h01) = o1;
    }
    __syncthreads();   // B: h2 visible before next step's B-operand reads
  }
}

// ---------------------------------------------------------------------------
extern "C" void kernel_launch(void* const* d_in, const int* in_sizes, int n_in,
                              void* d_out, int out_size, void* d_ws, size_t ws_size,
                              hipStream_t stream) {
  const float* v_in   = (const float*)d_in[0];
  const float* w_ih_f = (const float*)d_in[1];
  const float* w_hh_f = (const float*)d_in[2];
  const float* b_ih_f = (const float*)d_in[3];
  const float* b_hh_f = (const float*)d_in[4];
  const float* w_ih_b = (const float*)d_in[5];
  const float* w_hh_b = (const float*)d_in[6];
  const float* b_ih_b = (const float*)d_in[7];
  const float* b_hh_b = (const float*)d_in[8];
  const int*   clp    = (const int*)d_in[9];
  float* out = (float*)d_out;
  unsigned short* gi = (unsigned short*)d_ws;                    // 192 MiB
  unsigned int* flags = (unsigned int*)((char*)d_ws + GI_BYTES); // 16 counters

  zero_flags_k<<<dim3(1), dim3(64), 0, stream>>>(flags);
  fused_k<<<dim3(4 + NCHUNK * 384), dim3(512), 0, stream>>>(
      v_in, w_ih_f, w_hh_f, b_ih_f, b_hh_f,
      w_ih_b, w_hh_b, b_ih_b, b_hh_b, clp, gi, flags, out);
}

// Round 4
// 6512.444 us; speedup vs baseline: 1.1068x; 1.1068x over previous
//
#include <hip/hip_runtime.h>

typedef __attribute__((ext_vector_type(8))) short bf8_t;
typedef __attribute__((ext_vector_type(4))) float f32x4;
typedef __attribute__((ext_vector_type(4))) unsigned short us4;

#define S_LEN 2048
#define NCHUNK 16
#define CHUNK_TARGET 384u
#define GI_BYTES (65536ULL * 1536ULL * 2ULL)

static __device__ __forceinline__ unsigned short f2bf(float f) {
  union { float f; unsigned u; } v; v.f = f;
  unsigned r = v.u + 0x7FFFu + ((v.u >> 16) & 1u);
  return (unsigned short)(r >> 16);
}
static __device__ __forceinline__ float bf2f(unsigned short u) {
  union { unsigned u; float f; } v; v.u = ((unsigned)u) << 16;
  return v.f;
}
static __device__ __forceinline__ float sigm(float x) {
  return __builtin_amdgcn_rcpf(1.f + __expf(-x));   // overflow -> inf -> rcp -> 0: safe
}
static __device__ __forceinline__ float tanh_(float x) {
  return 1.f - 2.f * __builtin_amdgcn_rcpf(__expf(2.f * x) + 1.f);
}
static __device__ __forceinline__ f32x4 MFMA(bf8_t a, bf8_t b, f32x4 c) {
  return __builtin_amdgcn_mfma_f32_16x16x32_bf16(a, b, c, 0, 0, 0);
}

__global__ void zero_flags_k(unsigned int* f) {
  if (threadIdx.x < NCHUNK) f[threadIdx.x] = 0u;
}

union SMemU {
  struct { unsigned short As[128][40], Bs[128][40]; } g;                 // 20480 B
  struct { unsigned short h[2][16][264]; float bhn[256]; } r;           // 17920 B
};

// ---------------------------------------------------------------------------
// Fused kernel, 1024 threads (16 waves, 4/SIMD -> 128-reg budget).
// Blocks 0-3: GRU recurrence, block = (dir, 16-batch group). 16 real batch
// columns per MFMA (no lane duplication), in-register gates, one barrier/step.
// Blocks 4..6147: gi GEMM 128x128 tiles, chunk-ordered 0,15,1,14,... with
// per-chunk release counters; rec blocks acquire-poll per 128-t chunk.
// ---------------------------------------------------------------------------
__global__ __launch_bounds__(1024) void fused_k(
    const float* __restrict__ v_in,
    const float* __restrict__ Wif, const float* __restrict__ Whf,
    const float* __restrict__ bif, const float* __restrict__ bhf,
    const float* __restrict__ Wib, const float* __restrict__ Whb,
    const float* __restrict__ bib, const float* __restrict__ bhb,
    const int* __restrict__ clp,
    unsigned short* __restrict__ gi,
    unsigned int* flags,
    float* __restrict__ out)
{
  const int bid = blockIdx.x;
  const int tid = threadIdx.x;
  const int lane = tid & 63, wave = tid >> 6;
  const int l15 = lane & 15, l4 = lane >> 4;

  __shared__ SMemU sm;

  if (bid >= 4) {
    // ---------------- GEMM: gi = [X@Wf^T | X@Wb^T] + folded biases ---------
    const int gidb = bid - 4;
    const int cr = gidb / 384, sub = gidb % 384;
    const int bb = sub / 12, nb = sub % 12;
    const int c = (cr & 1) ? (15 - (cr >> 1)) : (cr >> 1);
    const int m0 = bb * 2048 + c * 128;
    const int n0 = nb * 128;
    const int wm = wave >> 3, wn = wave & 7;    // 2 x 8 waves, 64x16 each

    f32x4 acc[4];
#pragma unroll
    for (int a = 0; a < 4; ++a) acc[a] = f32x4{0.f, 0.f, 0.f, 0.f};

    const int sr = tid >> 3, sq = tid & 7;      // staging: 128 rows x 8 quads
    const int scg = n0 + sr;
    const float* spb = (scg < 768) ? (Wif + (size_t)scg * 256)
                                   : (Wib + (size_t)(scg - 768) * 256);
    const float* spa = v_in + (size_t)(m0 + sr) * 256;

    for (int k0 = 0; k0 < 256; k0 += 32) {
      float4 va = *(const float4*)(spa + k0 + sq * 4);
      unsigned long long pka =
          (unsigned long long)((unsigned)f2bf(va.x) | ((unsigned)f2bf(va.y) << 16)) |
          ((unsigned long long)((unsigned)f2bf(va.z) | ((unsigned)f2bf(va.w) << 16)) << 32);
      *(unsigned long long*)&sm.g.As[sr][sq * 4] = pka;
      float4 vb = *(const float4*)(spb + k0 + sq * 4);
      unsigned long long pkb =
          (unsigned long long)((unsigned)f2bf(vb.x) | ((unsigned)f2bf(vb.y) << 16)) |
          ((unsigned long long)((unsigned)f2bf(vb.z) | ((unsigned)f2bf(vb.w) << 16)) << 32);
      *(unsigned long long*)&sm.g.Bs[sr][sq * 4] = pkb;
      __syncthreads();
      bf8_t bv = *(const bf8_t*)&sm.g.Bs[wn * 16 + l15][l4 * 8];
#pragma unroll
      for (int mt = 0; mt < 4; ++mt) {
        bf8_t af = *(const bf8_t*)&sm.g.As[wm * 64 + mt * 16 + l15][l4 * 8];
        acc[mt] = MFMA(af, bv, acc[mt]);
      }
      __syncthreads();
    }
    {
      const int col = n0 + wn * 16 + l15;
      const int col3 = (col < 768) ? col : col - 768;
      const int gate = col3 >> 8;
      const float bias = ((col < 768) ? bif[col3] : bib[col3]) +
                         ((gate < 2) ? ((col < 768) ? bhf[col3] : bhb[col3]) : 0.f);
#pragma unroll
      for (int mt = 0; mt < 4; ++mt) {
        const int row = m0 + wm * 64 + mt * 16 + l4 * 4;
#pragma unroll
        for (int q = 0; q < 4; ++q)
          gi[(size_t)(row + q) * 1536 + col] = f2bf(acc[mt][q] + bias);
      }
    }
    __syncthreads();  // drains vmcnt: all gi stores of this block complete
    if (tid == 0)
      __hip_atomic_fetch_add(&flags[c], 1u, __ATOMIC_RELEASE, __HIP_MEMORY_SCOPE_AGENT);
    return;
  }

  // ---------------- Recurrence ---------------------------------------------
  const int dir = bid & 1;
  const int batch = (bid >> 1) * 16 + l15;
  const int cl = clp[0];
  const int rows = S_LEN - 2 * cl;
  const float* Wh = dir ? Whb : Whf;
  const float* bh = dir ? bhb : bhf;
  const int u0 = wave * 16 + l4 * 4;        // this lane's 4 hidden units

  // persistent W_hh fragments: gate-matched rows so gates are in-register.
  bf8_t afR[8], afZ[8], afN[8];             // 96 VGPRs
  {
    const float* wr = Wh + (size_t)(wave * 16 + l15) * 256 + l4 * 8;
    const float* wz = wr + 256 * 256;
    const float* wn_ = wr + 512 * 256;
#pragma unroll
    for (int c = 0; c < 8; ++c) {
      bf8_t f;
      float4 a0 = *(const float4*)(wr + c * 32), a1 = *(const float4*)(wr + c * 32 + 4);
      f[0]=(short)f2bf(a0.x); f[1]=(short)f2bf(a0.y); f[2]=(short)f2bf(a0.z); f[3]=(short)f2bf(a0.w);
      f[4]=(short)f2bf(a1.x); f[5]=(short)f2bf(a1.y); f[6]=(short)f2bf(a1.z); f[7]=(short)f2bf(a1.w);
      afR[c] = f;
      a0 = *(const float4*)(wz + c * 32); a1 = *(const float4*)(wz + c * 32 + 4);
      f[0]=(short)f2bf(a0.x); f[1]=(short)f2bf(a0.y); f[2]=(short)f2bf(a0.z); f[3]=(short)f2bf(a0.w);
      f[4]=(short)f2bf(a1.x); f[5]=(short)f2bf(a1.y); f[6]=(short)f2bf(a1.z); f[7]=(short)f2bf(a1.w);
      afZ[c] = f;
      a0 = *(const float4*)(wn_ + c * 32); a1 = *(const float4*)(wn_ + c * 32 + 4);
      f[0]=(short)f2bf(a0.x); f[1]=(short)f2bf(a0.y); f[2]=(short)f2bf(a0.z); f[3]=(short)f2bf(a0.w);
      f[4]=(short)f2bf(a1.x); f[5]=(short)f2bf(a1.y); f[6]=(short)f2bf(a1.z); f[7]=(short)f2bf(a1.w);
      afN[c] = f;
    }
  }
  if (tid < 256) sm.r.bhn[tid] = bh[512 + tid];
  for (int i = tid; i < 2 * 16 * 264; i += 1024) ((unsigned short*)sm.r.h)[i] = 0;
  __syncthreads();

  const unsigned short* gib = gi + (size_t)batch * (S_LEN * 1536) + dir * 768 + u0;
  float* ob = out + (size_t)batch * rows * 512 + dir * 256 + u0;

#pragma unroll 1
  for (int s = 0; s < S_LEN; ++s) {
    const int t = dir ? (S_LEN - 1 - s) : s;
    if ((s & 127) == 0) {                   // both dirs cross chunks here
      if (tid == 0) {
        unsigned int* fp = &flags[t >> 7];
        while (__hip_atomic_load(fp, __ATOMIC_RELAXED, __HIP_MEMORY_SCOPE_AGENT) < CHUNK_TARGET)
          __builtin_amdgcn_s_sleep(16);
        (void)__hip_atomic_load(fp, __ATOMIC_ACQUIRE, __HIP_MEMORY_SCOPE_AGENT);
      }
      __syncthreads();
    }
    // issue gate-input loads early; consumed after the MFMA phase
    const unsigned short* gt = gib + t * 1536;
    const us4 LR = *(const us4*)(gt);
    const us4 LZ = *(const us4*)(gt + 256);
    const us4 LN = *(const us4*)(gt + 512);

    const int p = s & 1;
    f32x4 aR = {0.f,0.f,0.f,0.f}, aZ = aR, aN = aR;
    const unsigned short* hb = &sm.r.h[p][l15][0];
#pragma unroll
    for (int c = 0; c < 8; ++c) {
      const bf8_t bv = *(const bf8_t*)(hb + c * 32 + l4 * 8);
      aR = MFMA(afR[c], bv, aR);
      aZ = MFMA(afZ[c], bv, aZ);
      aN = MFMA(afN[c], bv, aN);
    }
    const us4 HO = *(const us4*)&sm.r.h[p][l15][u0];
    const f32x4 BN = *(const f32x4*)&sm.r.bhn[u0];
    float h2[4]; us4 hw;
#pragma unroll
    for (int q = 0; q < 4; ++q) {
      const float r = sigm(aR[q] + bf2f(LR[q]));
      const float z = sigm(aZ[q] + bf2f(LZ[q]));
      const float n = tanh_(bf2f(LN[q]) + r * (aN[q] + BN[q]));
      const float ho = bf2f(HO[q]);
      h2[q] = n + z * (ho - n);
      hw[q] = f2bf(h2[q]);
    }
    *(us4*)&sm.r.h[p ^ 1][l15][u0] = hw;
    if (s >= cl && s < S_LEN - cl) {
      const float4 o = {h2[0], h2[1], h2[2], h2[3]};
      *(float4*)(ob + (size_t)(s - cl) * 512) = o;
    }
    __syncthreads();   // new h visible; old buffer free for overwrite next step
  }
}

// ---------------------------------------------------------------------------
// out[b][r][c] += v-term  (dir0: v[b][cl+r][c]; dir1: v[b][2047-cl-r][c-256])
// ---------------------------------------------------------------------------
__global__ __launch_bounds__(1024) void addv_k(
    const float* __restrict__ v, const int* __restrict__ clp,
    float* __restrict__ out)
{
  const int cl = clp[0];
  const int rows = S_LEN - 2 * cl;
  const int idx = blockIdx.x * 1024 + threadIdx.x;   // float4 slot
  const int b = idx >> 18;                            // 2048*128 = 2^18
  const int rem = idx & 262143;
  const int r = rem >> 7, c4 = rem & 127;
  if (r >= rows) return;
  const int col = c4 * 4;
  const float4 vv = (col < 256)
      ? *(const float4*)(v + (size_t)(b * 2048 + cl + r) * 256 + col)
      : *(const float4*)(v + (size_t)(b * 2048 + (2047 - cl - r)) * 256 + (col - 256));
  float4* po = (float4*)(out + ((size_t)b * rows + r) * 512 + col);
  float4 o = *po;
  o.x += vv.x; o.y += vv.y; o.z += vv.z; o.w += vv.w;
  *po = o;
}

// ---------------------------------------------------------------------------
extern "C" void kernel_launch(void* const* d_in, const int* in_sizes, int n_in,
                              void* d_out, int out_size, void* d_ws, size_t ws_size,
                              hipStream_t stream) {
  const float* v_in   = (const float*)d_in[0];
  const float* w_ih_f = (const float*)d_in[1];
  const float* w_hh_f = (const float*)d_in[2];
  const float* b_ih_f = (const float*)d_in[3];
  const float* b_hh_f = (const float*)d_in[4];
  const float* w_ih_b = (const float*)d_in[5];
  const float* w_hh_b = (const float*)d_in[6];
  const float* b_ih_b = (const float*)d_in[7];
  const float* b_hh_b = (const float*)d_in[8];
  const int*   clp    = (const int*)d_in[9];
  float* out = (float*)d_out;
  unsigned short* gi = (unsigned short*)d_ws;                    // 192 MiB
  unsigned int* flags = (unsigned int*)((char*)d_ws + GI_BYTES); // 16 counters

  zero_flags_k<<<dim3(1), dim3(64), 0, stream>>>(flags);
  fused_k<<<dim3(4 + NCHUNK * 384), dim3(1024), 0, stream>>>(
      v_in, w_ih_f, w_hh_f, b_ih_f, b_hh_f,
      w_ih_b, w_hh_b, b_ih_b, b_hh_b, clp, gi, flags, out);
  addv_k<<<dim3(8192), dim3(1024), 0, stream>>>(v_in, clp, out);
}